// Round 1
// baseline (1071.554 us; speedup 1.0000x reference)
//
#include <hip/hip_runtime.h>

#define KN  50
#define NM  10          // MBON == DAN == 10
#define LPB 16          // lanes per batch element

// ---- DPP helpers: sum across a 16-lane row (our batch group), result in all lanes ----
template <int CTRL>
__device__ __forceinline__ float dpp_mov_f(float x) {
  return __int_as_float(
      __builtin_amdgcn_update_dpp(0, __float_as_int(x), CTRL, 0xF, 0xF, true));
}

__device__ __forceinline__ float rowsum16(float x) {
  // circular-rotate reduction: after ror 1,2,4,8 every lane holds the row sum
  x += dpp_mov_f<0x121>(x);   // row_ror:1
  x += dpp_mov_f<0x122>(x);   // row_ror:2
  x += dpp_mov_f<0x124>(x);   // row_ror:4
  x += dpp_mov_f<0x128>(x);   // row_ror:8
  return x;
}

extern "C" __global__ void __launch_bounds__(256, 2)
fly_kernel(const float* __restrict__ odor,    // [T,B,3]
           const float* __restrict__ ctxp,    // [T,B,1]
           const float* __restrict__ pn_w,    // [B,3,KN]
           const float* __restrict__ kn_b,    // [KN]
           const float* __restrict__ apl_w,   // [KN,1]
           const float* __restrict__ apl_b,   // [1]
           const float* __restrict__ mdw_g,   // mbon_dan_weight [DAN,MBON]
           const float* __restrict__ mbon_b,  // [MBON]
           const float* __restrict__ dmw_g,   // dan_mbon_weight [MBON,DAN]
           const float* __restrict__ ddw_g,   // dan_dan_weight [DAN,DAN]
           const float* __restrict__ dcw_g,   // dan_context_weight [1,DAN]
           const float* __restrict__ dan_b,   // [DAN]
           const float* __restrict__ decW,    // [2,MBON]
           const float* __restrict__ decb,    // [2]
           const float* __restrict__ kcw0,    // [B,KN,MBON]
           const float* __restrict__ wact0,   // [B,KN,MBON]
           float* __restrict__ out,           // [T,B,2]
           int B, int T)
{
  const int tid = threadIdx.x;
  const int j   = tid & (LPB - 1);                    // lane within batch group
  const int b   = blockIdx.x * (256 / LPB) + (tid >> 4);
  if (b >= B) return;

  const bool has4 = (j + 48) < KN;                    // lanes 0,1 own a 4th k-row

  // ---- per-lane persistent plastic state + per-batch weights (registers only) ----
  float kcw[4][NM], wct[4][NM];
  float pw0[4], pw1[4], pw2[4], knb[4], aw[4];
  float kcn[4] = {0.f,0.f,0.f,0.f}, lkc[4] = {0.f,0.f,0.f,0.f};

  #pragma unroll
  for (int i = 0; i < 4; ++i) {
    const int k = j + 16 * i;
    if (i < 3 || has4) {
      const float2* a = reinterpret_cast<const float2*>(kcw0  + ((size_t)b * KN + k) * NM);
      const float2* w = reinterpret_cast<const float2*>(wact0 + ((size_t)b * KN + k) * NM);
      #pragma unroll
      for (int h = 0; h < 5; ++h) {
        float2 av = a[h], wv = w[h];
        kcw[i][2*h] = av.x; kcw[i][2*h+1] = av.y;
        wct[i][2*h] = wv.x; wct[i][2*h+1] = wv.y;
      }
      pw0[i] = pn_w[((size_t)b * 3 + 0) * KN + k];
      pw1[i] = pn_w[((size_t)b * 3 + 1) * KN + k];
      pw2[i] = pn_w[((size_t)b * 3 + 2) * KN + k];
      knb[i] = kn_b[k];
      aw[i]  = apl_w[k];
    } else {
      #pragma unroll
      for (int m = 0; m < NM; ++m) { kcw[i][m] = 0.f; wct[i][m] = 0.f; }
      pw0[i] = pw1[i] = pw2[i] = 0.f; knb[i] = 0.f; aw[i] = 0.f;
    }
  }

  // ---- per-column (m == j) small weights; lanes j>=10 hold zeros ----
  float mdw[NM], ddw[NM], dmw[NM];
  float cw = 0.f, db_ = 0.f, mb_ = 0.f, dw0 = 0.f, dw1 = 0.f;
  #pragma unroll
  for (int d = 0; d < NM; ++d) { mdw[d] = 0.f; ddw[d] = 0.f; dmw[d] = 0.f; }
  if (j < NM) {
    #pragma unroll
    for (int d = 0; d < NM; ++d) {
      mdw[d] = mdw_g[d * NM + j];   // mbon_dan_weight[:, j]
      ddw[d] = ddw_g[d * NM + j];   // dan_dan_weight[:, j]
      dmw[d] = dmw_g[d * NM + j];   // dan_mbon_weight[:, j]
    }
    cw  = dcw_g[j];
    db_ = dan_b[j];
    mb_ = mbon_b[j];
    dw0 = decW[j];
    dw1 = decW[NM + j];
  }
  const float aplb = apl_b[0];
  const float db0 = decb[0], db1 = decb[1];

  const float ALPHA = (float)(0.5 / 5.5);   // DT/(DT+RC)
  const float OMA   = 1.0f - ALPHA;

  // ---- recurrent small state ----
  float apl = 0.f, mbon_m = 0.f, dan_m = 0.f;
  float dvec[NM], ldv[NM];
  #pragma unroll
  for (int m = 0; m < NM; ++m) { dvec[m] = 0.f; ldv[m] = 0.f; }

  for (int t = 0; t < T; ++t) {
    const size_t ob = ((size_t)t * B + b) * 3;
    const float o0 = odor[ob], o1 = odor[ob + 1], o2 = odor[ob + 2];
    const float cxv = ctxp[(size_t)t * B + b];

    // --- Kenyon update (own k-rows) + kc_value/apl partial sums ---
    float psum = 0.f;
    float p[NM];
    #pragma unroll
    for (int m = 0; m < NM; ++m) p[m] = 0.f;

    #pragma unroll
    for (int i = 0; i < 4; ++i) {
      if (i < 3 || has4) {
        float pv = pw0[i] * o0 + pw1[i] * o1 + pw2[i] * o2;
        float r  = fmaxf(pv - apl + knb[i], 0.f);
        float kn = 0.5f * kcn[i] + 0.5f * r;        // dt_tau = 0.5
        kcn[i] = kn;
        lkc[i] = ALPHA * kn + OMA * lkc[i];         // low_kc_n (uses new kc_n)
        psum += kn * aw[i];
        #pragma unroll
        for (int m = 0; m < NM; ++m) p[m] += kn * kcw[i][m];   // kc_value vs pre-update kc_w
      }
    }

    psum = rowsum16(psum);
    #pragma unroll
    for (int m = 0; m < NM; ++m) p[m] = rowsum16(p[m]);

    apl = 0.5f * apl + 0.5f * fmaxf(psum + aplb, 0.f);

    float kcv = p[0];
    #pragma unroll
    for (int m = 1; m < NM; ++m) kcv = (j == m) ? p[m] : kcv;

    // --- MBON (column j): dan_mod uses PREVIOUS dan (dvec still old) ---
    float s = 0.f;
    #pragma unroll
    for (int d = 0; d < NM; ++d) s += dvec[d] * mdw[d];
    float dmod = 1.f / (1.f + __expf(-s));
    mbon_m = 0.5f * mbon_m + 0.5f * dmod * fmaxf(kcv + mb_, 0.f);

    float mvec[NM];
    #pragma unroll
    for (int m = 0; m < NM; ++m) mvec[m] = __shfl(mbon_m, m, LPB);

    // --- DAN (column j): uses previous dan (dvec) + new mbon (mvec) ---
    float dp = db_ + cxv * cw;
    #pragma unroll
    for (int e = 0; e < NM; ++e) dp += dvec[e] * ddw[e];
    #pragma unroll
    for (int m = 0; m < NM; ++m) dp += mvec[m] * dmw[m];
    dan_m = 0.5f * dan_m + 0.5f * fmaxf(dp, 0.f);

    #pragma unroll
    for (int m = 0; m < NM; ++m) dvec[m] = __shfl(dan_m, m, LPB);   // new dan, replicated
    #pragma unroll
    for (int m = 0; m < NM; ++m) ldv[m] = ALPHA * dvec[m] + OMA * ldv[m];  // low_dan_n

    // --- decoder output ---
    float q0 = rowsum16(mbon_m * dw0) + db0;
    float q1 = rowsum16(mbon_m * dw1) + db1;
    if (j == 0) {
      float2 st; st.x = q0; st.y = q1;
      *reinterpret_cast<float2*>(out + ((size_t)t * B + b) * 2) = st;
    }

    // --- plasticity: kc_w decays toward OLD wact, then wact += DT*syn ---
    #pragma unroll
    for (int i = 0; i < 4; ++i) {
      if (i < 3 || has4) {
        const float kh  =  0.5f * kcn[i];    // DT * kc_n
        const float nlh = -0.5f * lkc[i];    // -DT * low_kc_n
        #pragma unroll
        for (int m = 0; m < NM; ++m) {
          float w = wct[i][m];
          kcw[i][m] = 0.75f * kcw[i][m] + 0.25f * w;       // uses wact BEFORE syn
          wct[i][m] = w + kh * ldv[m] + nlh * dvec[m];     // wact_n
        }
      }
    }
  }
}

extern "C" void kernel_launch(void* const* d_in, const int* in_sizes, int n_in,
                              void* d_out, int out_size, void* d_ws, size_t ws_size,
                              hipStream_t stream) {
  const float* odor   = (const float*)d_in[0];
  const float* ctx    = (const float*)d_in[1];
  const float* pn_w   = (const float*)d_in[2];
  const float* kn_b   = (const float*)d_in[3];
  const float* apl_w  = (const float*)d_in[4];
  const float* apl_b  = (const float*)d_in[5];
  const float* mdw    = (const float*)d_in[6];
  const float* mbon_b = (const float*)d_in[7];
  const float* dmw    = (const float*)d_in[8];
  const float* ddw    = (const float*)d_in[9];
  const float* dcw    = (const float*)d_in[10];
  const float* dan_b  = (const float*)d_in[11];
  const float* decW   = (const float*)d_in[12];
  const float* decb   = (const float*)d_in[13];
  const float* kcw0   = (const float*)d_in[14];
  const float* wact0  = (const float*)d_in[15];
  float* out = (float*)d_out;

  const int B = in_sizes[14] / (KN * NM);   // kc_weight0 is [B,50,10]
  const int T = in_sizes[0] / (B * 3);      // odor is [T,B,3]

  const int batches_per_block = 256 / LPB;  // 16
  dim3 grid((B + batches_per_block - 1) / batches_per_block);
  dim3 block(256);
  hipLaunchKernelGGL(fly_kernel, grid, block, 0, stream,
                     odor, ctx, pn_w, kn_b, apl_w, apl_b,
                     mdw, mbon_b, dmw, ddw, dcw, dan_b,
                     decW, decb, kcw0, wact0, out, B, T);
}

// Round 2
// 824.170 us; speedup vs baseline: 1.3002x; 1.3002x over previous
//
#include <hip/hip_runtime.h>

#define KN  50
#define NM  10          // MBON == DAN == 10
#define LPB 16          // lanes per batch element

typedef float v2f __attribute__((ext_vector_type(2)));

// mov_dpp(old=0,bound_ctrl=1) + fadd; GCNDPPCombine fuses into v_add_f32_dpp (1 inst)
template <int CTRL>
__device__ __forceinline__ float dpp_add(float x) {
  return x + __int_as_float(
      __builtin_amdgcn_update_dpp(0, __float_as_int(x), CTRL, 0xF, 0xF, true));
}

__device__ __forceinline__ float rowsum16(float x) {
  x = dpp_add<0x121>(x);   // row_ror:1
  x = dpp_add<0x122>(x);   // row_ror:2
  x = dpp_add<0x124>(x);   // row_ror:4
  x = dpp_add<0x128>(x);   // row_ror:8
  return x;
}

__device__ __forceinline__ float bcast(int idx4, float x) {
  return __int_as_float(__builtin_amdgcn_ds_bpermute(idx4, __float_as_int(x)));
}

extern "C" __global__ void __launch_bounds__(256)
__attribute__((amdgpu_waves_per_eu(2, 2)))   // pin 2 waves/SIMD -> 256-VGPR budget, no AGPR spill copies
fly_kernel(const float* __restrict__ odor,    // [T,B,3]
           const float* __restrict__ ctxp,    // [T,B,1]
           const float* __restrict__ pn_w,    // [B,3,KN]
           const float* __restrict__ kn_b,    // [KN]
           const float* __restrict__ apl_w,   // [KN,1]
           const float* __restrict__ apl_b,   // [1]
           const float* __restrict__ mdw_g,   // mbon_dan_weight [DAN,MBON]
           const float* __restrict__ mbon_b,  // [MBON]
           const float* __restrict__ dmw_g,   // dan_mbon_weight [MBON,DAN]
           const float* __restrict__ ddw_g,   // dan_dan_weight [DAN,DAN]
           const float* __restrict__ dcw_g,   // dan_context_weight [1,DAN]
           const float* __restrict__ dan_b,   // [DAN]
           const float* __restrict__ decW,    // [2,MBON]
           const float* __restrict__ decb,    // [2]
           const float* __restrict__ kcw0,    // [B,KN,MBON]
           const float* __restrict__ wact0,   // [B,KN,MBON]
           float* __restrict__ out,           // [T,B,2]
           int B, int T)
{
  const int tid   = threadIdx.x;
  const int j     = tid & (LPB - 1);
  const int jhalf = j >> 1;
  const int jodd  = j & 1;
  const int b     = blockIdx.x * (256 / LPB) + (tid >> 4);
  if (b >= B) return;

  const int base4 = (tid & 48) << 2;          // byte index of lane 0 of this 16-lane group
  const bool has4 = (j + 48) < KN;            // lanes 0,1 own a 4th k-row

  // ---- persistent plastic state + per-batch weights (VGPRs) ----
  v2f   kcw[4][5], wct[4][5];                 // rows j,16+j,32+j,48+j  x  10 cols (packed)
  float pw0[4], pw1[4], pw2[4], knb[4], aw[4];
  float kcn[4] = {0.f,0.f,0.f,0.f}, lkc[4] = {0.f,0.f,0.f,0.f};

  #pragma unroll
  for (int i = 0; i < 4; ++i) {
    const int k = j + 16 * i;
    if (i < 3 || has4) {
      const v2f* a = reinterpret_cast<const v2f*>(kcw0  + ((size_t)b * KN + k) * NM);
      const v2f* w = reinterpret_cast<const v2f*>(wact0 + ((size_t)b * KN + k) * NM);
      #pragma unroll
      for (int h = 0; h < 5; ++h) { kcw[i][h] = a[h]; wct[i][h] = w[h]; }
      pw0[i] = pn_w[((size_t)b * 3 + 0) * KN + k];
      pw1[i] = pn_w[((size_t)b * 3 + 1) * KN + k];
      pw2[i] = pn_w[((size_t)b * 3 + 2) * KN + k];
      knb[i] = kn_b[k];
      aw[i]  = apl_w[k];
    } else {
      #pragma unroll
      for (int h = 0; h < 5; ++h) { kcw[i][h] = (v2f)(0.f); wct[i][h] = (v2f)(0.f); }
      pw0[i] = pw1[i] = pw2[i] = 0.f; knb[i] = 0.f; aw[i] = 0.f;
    }
  }

  // ---- per-column (m == j) small weights; lanes j>=10 hold zeros ----
  v2f   mdw2[5], ddw2[5];
  float dmw[NM];
  float cw = 0.f, db_ = 0.f, mb_ = 0.f, dw0 = 0.f, dw1 = 0.f;
  #pragma unroll
  for (int h = 0; h < 5; ++h) { mdw2[h] = (v2f)(0.f); ddw2[h] = (v2f)(0.f); }
  #pragma unroll
  for (int m = 0; m < NM; ++m) dmw[m] = 0.f;
  if (j < NM) {
    #pragma unroll
    for (int h = 0; h < 5; ++h) {
      mdw2[h].x = mdw_g[(2*h)   * NM + j];  mdw2[h].y = mdw_g[(2*h+1) * NM + j];
      ddw2[h].x = ddw_g[(2*h)   * NM + j];  ddw2[h].y = ddw_g[(2*h+1) * NM + j];
    }
    #pragma unroll
    for (int m = 0; m < NM; ++m) dmw[m] = dmw_g[m * NM + j];
    cw  = dcw_g[j];
    db_ = dan_b[j];
    mb_ = mbon_b[j];
    dw0 = decW[j];
    dw1 = decW[NM + j];
  }
  const float aplb = apl_b[0];
  const float db0 = decb[0], db1 = decb[1];

  const float ALPHA = (float)(0.5 / 5.5);     // DT/(DT+RC)

  // ---- recurrent small state ----
  float apl = 0.f, mbon_m = 0.f, dan_m = 0.f;
  v2f dvec2[5], ldv2[5];
  #pragma unroll
  for (int h = 0; h < 5; ++h) { dvec2[h] = (v2f)(0.f); ldv2[h] = (v2f)(0.f); }

  // prefetch t=0 inputs
  size_t ob = (size_t)b * 3;
  float o0n = odor[ob], o1n = odor[ob + 1], o2n = odor[ob + 2];
  float cxn = ctxp[b];

  for (int t = 0; t < T; ++t) {
    const float o0 = o0n, o1 = o1n, o2 = o2n, cx = cxn;
    // prefetch next step's inputs (clamped at end)
    {
      const int tn = (t + 1 < T) ? t + 1 : t;
      const size_t obn = ((size_t)tn * B + b) * 3;
      o0n = odor[obn]; o1n = odor[obn + 1]; o2n = odor[obn + 2];
      cxn = ctxp[(size_t)tn * B + b];
    }

    // --- Kenyon update (own k-rows) + packed kc_value/apl partial sums ---
    float psum = 0.f;
    v2f p2[5];
    #pragma unroll
    for (int h = 0; h < 5; ++h) p2[h] = (v2f)(0.f);

    #pragma unroll
    for (int i = 0; i < 4; ++i) {
      if (i < 3 || has4) {
        float pv = fmaf(pw0[i], o0, fmaf(pw1[i], o1, pw2[i] * o2));
        float r  = fmaxf(pv - apl + knb[i], 0.f);
        float kn = 0.5f * (kcn[i] + r);             // dt_tau = 0.5
        kcn[i] = kn;
        lkc[i] = fmaf(ALPHA, kn - lkc[i], lkc[i]);  // low_kc_n (new kc_n)
        psum = fmaf(kn, aw[i], psum);
        #pragma unroll
        for (int h = 0; h < 5; ++h) p2[h] += kn * kcw[i][h];  // vs pre-update kc_w
      }
    }

    psum = rowsum16(psum);
    #pragma unroll
    for (int h = 0; h < 5; ++h) {
      p2[h].x = rowsum16(p2[h].x);
      p2[h].y = rowsum16(p2[h].y);
    }

    apl = 0.5f * apl + 0.5f * fmaxf(psum + aplb, 0.f);

    // select this lane's column value
    v2f rsel = p2[0];
    #pragma unroll
    for (int h = 1; h < 5; ++h) rsel = (jhalf == h) ? p2[h] : rsel;
    const float kcv = jodd ? rsel.y : rsel.x;

    // --- MBON (column j): dan_mod uses PREVIOUS dan ---
    v2f s2 = dvec2[0] * mdw2[0];
    #pragma unroll
    for (int e = 1; e < 5; ++e) s2 += dvec2[e] * mdw2[e];
    const float s = s2.x + s2.y;
    const float dmod = 1.f / (1.f + __expf(-s));
    mbon_m = 0.5f * mbon_m + 0.5f * dmod * fmaxf(kcv + mb_, 0.f);

    // --- DAN (column j): previous dan + new mbon (fused broadcast) ---
    v2f dp2 = dvec2[0] * ddw2[0];
    #pragma unroll
    for (int e = 1; e < 5; ++e) dp2 += dvec2[e] * ddw2[e];
    float dp = dp2.x + dp2.y + fmaf(cx, cw, db_);
    #pragma unroll
    for (int m = 0; m < NM; ++m)
      dp = fmaf(bcast(base4 + 4 * m, mbon_m), dmw[m], dp);
    dan_m = 0.5f * dan_m + 0.5f * fmaxf(dp, 0.f);

    // broadcast new dan to all 16 lanes; update low_dan
    #pragma unroll
    for (int e = 0; e < 5; ++e) {
      dvec2[e].x = bcast(base4 + 8 * e,     dan_m);
      dvec2[e].y = bcast(base4 + 8 * e + 4, dan_m);
      ldv2[e] += ALPHA * (dvec2[e] - ldv2[e]);      // low_dan_n (new dan)
    }

    // --- decoder output ---
    const float q0 = rowsum16(mbon_m * dw0) + db0;
    const float q1 = rowsum16(mbon_m * dw1) + db1;
    if (j == 0) {
      float2 st; st.x = q0; st.y = q1;
      *reinterpret_cast<float2*>(out + ((size_t)t * B + b) * 2) = st;
    }

    // --- plasticity (packed): kc_w decays toward OLD wact, then wact += DT*syn ---
    #pragma unroll
    for (int i = 0; i < 4; ++i) {
      if (i < 3 || has4) {
        const float kh  =  0.5f * kcn[i];    // DT * kc_n
        const float nlh = -0.5f * lkc[i];    // -DT * low_kc_n
        #pragma unroll
        for (int h = 0; h < 5; ++h) {
          const v2f w = wct[i][h];
          kcw[i][h] = 0.75f * kcw[i][h] + 0.25f * w;       // uses wact BEFORE syn
          wct[i][h] = w + kh * ldv2[h] + nlh * dvec2[h];   // wact_n
        }
      }
    }
  }
}

extern "C" void kernel_launch(void* const* d_in, const int* in_sizes, int n_in,
                              void* d_out, int out_size, void* d_ws, size_t ws_size,
                              hipStream_t stream) {
  const float* odor   = (const float*)d_in[0];
  const float* ctx    = (const float*)d_in[1];
  const float* pn_w   = (const float*)d_in[2];
  const float* kn_b   = (const float*)d_in[3];
  const float* apl_w  = (const float*)d_in[4];
  const float* apl_b  = (const float*)d_in[5];
  const float* mdw    = (const float*)d_in[6];
  const float* mbon_b = (const float*)d_in[7];
  const float* dmw    = (const float*)d_in[8];
  const float* ddw    = (const float*)d_in[9];
  const float* dcw    = (const float*)d_in[10];
  const float* dan_b  = (const float*)d_in[11];
  const float* decW   = (const float*)d_in[12];
  const float* decb   = (const float*)d_in[13];
  const float* kcw0   = (const float*)d_in[14];
  const float* wact0  = (const float*)d_in[15];
  float* out = (float*)d_out;

  const int B = in_sizes[14] / (KN * NM);   // kc_weight0 is [B,50,10]
  const int T = in_sizes[0] / (B * 3);      // odor is [T,B,3]

  const int batches_per_block = 256 / LPB;  // 16
  dim3 grid((B + batches_per_block - 1) / batches_per_block);
  dim3 block(256);
  hipLaunchKernelGGL(fly_kernel, grid, block, 0, stream,
                     odor, ctx, pn_w, kn_b, apl_w, apl_b,
                     mdw, mbon_b, dmw, ddw, dcw, dan_b,
                     decW, decb, kcw0, wact0, out, B, T);
}